// Round 4
// baseline (708.279 us; speedup 1.0000x reference)
//
#include <hip/hip_runtime.h>
#include <hip/hip_bf16.h>

#define N_NODES 100000
#define N_EDGES 1600000
#define F_IN    128
#define H       256
#define NHID    512
#define NOUT    256
#define G_GR    256

typedef unsigned short u16;
typedef unsigned int u32;
typedef __attribute__((ext_vector_type(8))) short s16x8;
typedef __attribute__((ext_vector_type(8))) unsigned short u16x8;
typedef __attribute__((ext_vector_type(4))) float f32x4;

// edge entry encoding: (src:17b | indeg_src:15b). wt recomputed as
// dinv[dst]*rsqrtf(1+deg) — bit-identical to storing the product.
#define SRC_MASK 0x1FFFFu
#define DEG_SHIFT 17
// node sort key: (batch:8b)*64 + min(deg,63) — groups equal-degree nodes within a
// graph so co-scheduled (half/quarter-)waves have equal trip counts. 16384 bins.
#define NKEYS (G_GR * 64)

__device__ __forceinline__ float bf2f(u16 u) {
    union { unsigned int i; float f; } v; v.i = ((unsigned int)u) << 16; return v.f;
}
__device__ __forceinline__ u16 f2bf(float f) {
    union { float f; unsigned int i; } v; v.f = f;
    unsigned int x = v.i;
    x += 0x7fffu + ((x >> 16) & 1u);
    return (u16)(x >> 16);
}

// ---------------- head: count_deg (atomics) + LDS-tiled weight transposes + goff -----
#define CD_BLKS   1563                        // 4 strided edges/thread (R8 known-good form)
#define SPX_BLKS  ((N_NODES * F_IN) / 1024)   // 12500 — carried by scatter kernel
#define T1_TILES  ((F_IN / 64) * (H / 64))    // 8
#define T2_TILES  ((H / 64) * (H / 64))       // 16
#define T3_TILES  ((H / 64) * (H / 64))       // 16
#define TM1_TILES ((H / 64) * (NHID / 64))    // 32
#define TM2_TILES ((NHID / 64) * (NOUT / 64)) // 32
#define HEAD_BLKS (CD_BLKS + T1_TILES + T2_TILES + T3_TILES + TM1_TILES + TM2_TILES + 2)

// 64x64 tile transpose via padded LDS: coalesced f32 reads, coalesced 2B hi/lo stores.
__device__ __forceinline__ void transpose_tile(float (*tile)[65],
        const float* __restrict__ W, u16* __restrict__ thi, u16* __restrict__ tlo,
        int K, int N, int tileIdx) {
    const int ntn = N >> 6;
    const int tk = tileIdx / ntn, tn = tileIdx - tk * ntn;
    const int t = threadIdx.x;
    const int c = t & 63, r4 = t >> 6;
#pragma unroll
    for (int i = 0; i < 64; i += 4)
        tile[r4 + i][c] = W[(size_t)(tk * 64 + r4 + i) * N + tn * 64 + c];
    __syncthreads();
#pragma unroll
    for (int i = 0; i < 64; i += 4) {
        int n = tn * 64 + r4 + i, k = tk * 64 + c;
        float f = tile[c][r4 + i];
        u16 h = f2bf(f);
        thi[(size_t)n * K + k] = h;
        tlo[(size_t)n * K + k] = f2bf(f - bf2f(h));
    }
}

__global__ __launch_bounds__(256) void prep_head(
        const int* __restrict__ dst, int* __restrict__ degc,
        const float* __restrict__ W1, u16* __restrict__ t1h, u16* __restrict__ t1l,
        const float* __restrict__ W2, u16* __restrict__ t2h, u16* __restrict__ t2l,
        const float* __restrict__ W3, u16* __restrict__ t3h, u16* __restrict__ t3l,
        const float* __restrict__ Wm1, u16* __restrict__ tm1h, u16* __restrict__ tm1l,
        const float* __restrict__ Wm2, u16* __restrict__ tm2h, u16* __restrict__ tm2l,
        const int* __restrict__ batch, int* __restrict__ goff) {
    __shared__ float tile[64][65];
    int bid = blockIdx.x;
    if (bid < CD_BLKS) {
        int base = bid * 1024 + threadIdx.x;
#pragma unroll
        for (int q = 0; q < 4; q++) {
            int e = base + q * 256;
            if (e < N_EDGES) atomicAdd(&degc[dst[e]], 1);
        }
        return;
    }
    bid -= CD_BLKS;
    if (bid < T1_TILES) { transpose_tile(tile, W1, t1h, t1l, F_IN, H, bid); return; }
    bid -= T1_TILES;
    if (bid < T2_TILES) { transpose_tile(tile, W2, t2h, t2l, H, H, bid); return; }
    bid -= T2_TILES;
    if (bid < T3_TILES) { transpose_tile(tile, W3, t3h, t3l, H, H, bid); return; }
    bid -= T3_TILES;
    if (bid < TM1_TILES) { transpose_tile(tile, Wm1, tm1h, tm1l, H, NHID, bid); return; }
    bid -= TM1_TILES;
    if (bid < TM2_TILES) { transpose_tile(tile, Wm2, tm2h, tm2l, NHID, NOUT, bid); return; }
    bid -= TM2_TILES;
    {
        int g = bid * 256 + threadIdx.x;
        if (g > G_GR) return;
        int lo = 0, hi = N_NODES;
        while (lo < hi) {
            int mid = (lo + hi) >> 1;
            if (batch[mid] < g) lo = mid + 1; else hi = mid;
        }
        goff[g] = lo;
    }
}

// ---------------- scan (CSR rowp) ----------------
__global__ void scan_partial(const int* __restrict__ cnt, int* __restrict__ partial) {
    __shared__ int s[256];
    int t = threadIdx.x;
    int i = blockIdx.x * 256 + t;
    int v = (i < N_NODES) ? cnt[i] : 0;
    s[t] = v; __syncthreads();
    for (int off = 128; off > 0; off >>= 1) {
        if (t < off) s[t] += s[t + off];
        __syncthreads();
    }
    if (t == 0) partial[blockIdx.x] = s[0];
}

__global__ void scan_offsets(int* __restrict__ partial, int nb, int* __restrict__ rowp) {
    __shared__ int s[512];
    int t = threadIdx.x;
    int orig = (t < nb) ? partial[t] : 0;
    s[t] = orig; __syncthreads();
    for (int off = 1; off < 512; off <<= 1) {
        int u = (t >= off) ? s[t - off] : 0;
        __syncthreads();
        s[t] += u;
        __syncthreads();
    }
    if (t < nb) partial[t] = s[t] - orig;
    if (t == 0) rowp[N_NODES] = N_EDGES;
}

__global__ void scan_final_dinv(const int* __restrict__ cnt, const int* __restrict__ partial,
                                int* __restrict__ rowp, int* __restrict__ cur,
                                float* __restrict__ dinv, u32* __restrict__ pack,
                                const int* __restrict__ bat, int* __restrict__ khist) {
    __shared__ int s[256];
    int t = threadIdx.x;
    int i = blockIdx.x * 256 + t;
    int v = (i < N_NODES) ? cnt[i] : 0;
    s[t] = v; __syncthreads();
    for (int off = 1; off < 256; off <<= 1) {
        int u = (t >= off) ? s[t - off] : 0;
        __syncthreads();
        s[t] += u;
        __syncthreads();
    }
    if (i < N_NODES) {
        int r = partial[blockIdx.x] + s[t] - v;
        rowp[i] = r;
        cur[i] = r;
        dinv[i] = rsqrtf(1.0f + (float)v);
        pack[i] = (u32)i | ((u32)v << DEG_SHIFT);
        int d = v > 63 ? 63 : v;
        atomicAdd(&khist[bat[i] * 64 + d], 1);
    }
}

// ---------------- node sort: exclusive scan of 16384-bin hist, then scatter perm ----
__global__ __launch_bounds__(256) void scan_hist(const int* __restrict__ khist,
                                                 int* __restrict__ kcur) {
    __shared__ int s[256];
    int t = threadIdx.x;
    int base = t * (NKEYS / 256);
    int sum = 0;
    for (int j = 0; j < NKEYS / 256; j++) sum += khist[base + j];
    s[t] = sum; __syncthreads();
    int own = sum;
    for (int off = 1; off < 256; off <<= 1) {
        int u = (t >= off) ? s[t - off] : 0;
        __syncthreads();
        s[t] += u;
        __syncthreads();
    }
    int running = s[t] - own;   // exclusive prefix
    for (int j = 0; j < NKEYS / 256; j++) {
        kcur[base + j] = running;
        running += khist[base + j];
    }
}

__global__ void perm_scatter(const int* __restrict__ cnt, const int* __restrict__ bat,
                             int* __restrict__ kcur, int* __restrict__ perm) {
    int i = blockIdx.x * 256 + threadIdx.x;
    if (i < N_NODES) {
        int d = cnt[i]; if (d > 63) d = 63;
        int pos = atomicAdd(&kcur[bat[i] * 64 + d], 1);
        perm[pos] = i;
    }
}

// ---------------- scatter (packed 4B entries) + split_x streaming freight ----------------
__global__ __launch_bounds__(256) void scatter_splitx(
        const int* __restrict__ src, const int* __restrict__ dst,
        const u32* __restrict__ pack, int* __restrict__ cur,
        u32* __restrict__ ep4,
        const float* __restrict__ x, u16* __restrict__ x_bf) {
    int bid = blockIdx.x;
    if (bid < CD_BLKS) {
        int base = bid * 1024 + threadIdx.x;
#pragma unroll
        for (int q = 0; q < 4; q++) {
            int e = base + q * 256;
            if (e < N_EDGES) {
                int d = dst[e];
                int s = src[e];
                u32 pk = pack[s];
                int pos = atomicAdd(&cur[d], 1);
                ep4[pos] = pk;
            }
        }
        return;
    }
    bid -= CD_BLKS;
    {   // split_x: 4 floats/thread, 12500 blocks
        int idx = bid * 256 + threadIdx.x;
        float4 f = *(const float4*)&x[(size_t)idx * 4];
        ushort4 o;
        o.x = f2bf(f.x); o.y = f2bf(f.y); o.z = f2bf(f.z); o.w = f2bf(f.w);
        *(ushort4*)&x_bf[(size_t)idx * 4] = o;
    }
}

// ---------------- aggregation: half-wave (32 lanes x ushort8) per node, H=256 ----------------
__global__ __launch_bounds__(256) void gcn_agg256(
        const u16* __restrict__ in, const int* __restrict__ rowp,
        const u32* __restrict__ ep4, const float* __restrict__ dinv,
        const int* __restrict__ perm, u16* __restrict__ outp) {
    int node = perm[blockIdx.x * 8 + (threadIdx.x >> 5)];
    int l = threadIdx.x & 31;
    int beg = rowp[node], end = rowp[node + 1];
    float dnode = dinv[node];
    float a[8] = {};
    int e = beg;
    u32 pr[8];
    bool have = (e + 8 <= end);
    if (have) {
#pragma unroll
        for (int q = 0; q < 8; q++) pr[q] = ep4[e + q];
    }
    while (have) {
        u32 g8[8];
#pragma unroll
        for (int q = 0; q < 8; q++) g8[q] = pr[q];
        int en = e + 8;
        bool haven = (en + 8 <= end);
        if (haven) {
#pragma unroll
            for (int q = 0; q < 8; q++) pr[q] = ep4[en + q];
        }
#pragma unroll
        for (int q = 0; q < 8; q++) {
            u16x8 u = *(const u16x8*)&in[(size_t)(g8[q] & SRC_MASK) * H + l * 8];
            float wt = dnode * rsqrtf(1.0f + (float)(g8[q] >> DEG_SHIFT));
#pragma unroll
            for (int r = 0; r < 8; r++) a[r] += bf2f(u[r]) * wt;
        }
        e = en; have = haven;
    }
    for (; e < end; e++) {
        u32 pe = ep4[e];
        float wt = dnode * rsqrtf(1.0f + (float)(pe >> DEG_SHIFT));
        u16x8 u = *(const u16x8*)&in[(size_t)(pe & SRC_MASK) * H + l * 8];
#pragma unroll
        for (int r = 0; r < 8; r++) a[r] += bf2f(u[r]) * wt;
    }
    u16x8 us = *(const u16x8*)&in[(size_t)node * H + l * 8];
    float dd = dnode * dnode;
    u16x8 o;
#pragma unroll
    for (int r = 0; r < 8; r++) o[r] = f2bf(a[r] + bf2f(us[r]) * dd);
    *(u16x8*)&outp[(size_t)node * H + l * 8] = o;
}

// ---------------- aggregation: quarter-wave (16 lanes x ushort8) per node, F=128 ----------------
__global__ __launch_bounds__(256) void gcn_agg128(
        const u16* __restrict__ in, const int* __restrict__ rowp,
        const u32* __restrict__ ep4, const float* __restrict__ dinv,
        const int* __restrict__ perm, u16* __restrict__ outp) {
    int node = perm[blockIdx.x * 16 + (threadIdx.x >> 4)];
    int l = threadIdx.x & 15;
    int beg = rowp[node], end = rowp[node + 1];
    float dnode = dinv[node];
    float a[8] = {};
    int e = beg;
    u32 pr[8];
    bool have = (e + 8 <= end);
    if (have) {
#pragma unroll
        for (int q = 0; q < 8; q++) pr[q] = ep4[e + q];
    }
    while (have) {
        u32 g8[8];
#pragma unroll
        for (int q = 0; q < 8; q++) g8[q] = pr[q];
        int en = e + 8;
        bool haven = (en + 8 <= end);
        if (haven) {
#pragma unroll
            for (int q = 0; q < 8; q++) pr[q] = ep4[en + q];
        }
#pragma unroll
        for (int q = 0; q < 8; q++) {
            u16x8 u = *(const u16x8*)&in[(size_t)(g8[q] & SRC_MASK) * F_IN + l * 8];
            float wt = dnode * rsqrtf(1.0f + (float)(g8[q] >> DEG_SHIFT));
#pragma unroll
            for (int r = 0; r < 8; r++) a[r] += bf2f(u[r]) * wt;
        }
        e = en; have = haven;
    }
    for (; e < end; e++) {
        u32 pe = ep4[e];
        float wt = dnode * rsqrtf(1.0f + (float)(pe >> DEG_SHIFT));
        u16x8 u = *(const u16x8*)&in[(size_t)(pe & SRC_MASK) * F_IN + l * 8];
#pragma unroll
        for (int r = 0; r < 8; r++) a[r] += bf2f(u[r]) * wt;
    }
    u16x8 us = *(const u16x8*)&in[(size_t)node * F_IN + l * 8];
    float dd = dnode * dnode;
    u16x8 o;
#pragma unroll
    for (int r = 0; r < 8; r++) o[r] = f2bf(a[r] + bf2f(us[r]) * dd);
    *(u16x8*)&outp[(size_t)node * F_IN + l * 8] = o;
}

// ---------------- layer-3 fused agg+pool: gather form, no per-node output ----------------
// perm is sorted primarily by batch, so batch[perm[i]] is non-decreasing and the
// per-block graph-slot reduce logic is unchanged.
__global__ __launch_bounds__(256) void gcn_agg_pool(
        const u16* __restrict__ in, const int* __restrict__ rowp,
        const u32* __restrict__ ep4, const float* __restrict__ dinv,
        const int* __restrict__ perm, const int* __restrict__ batch,
        float* __restrict__ poolacc) {
    __shared__ __align__(16) float pacc[8][H];
    __shared__ int gslot[8];
    const int tid = threadIdx.x;
    const int hw = tid >> 5;
    const int l = tid & 31;
    const int node = perm[blockIdx.x * 8 + hw];
    const int gbase = batch[perm[blockIdx.x * 8]];

    int beg = rowp[node], end = rowp[node + 1];
    float dnode = dinv[node];
    float a[8] = {};
    int e = beg;
    u32 pr[8];
    bool have = (e + 8 <= end);
    if (have) {
#pragma unroll
        for (int q = 0; q < 8; q++) pr[q] = ep4[e + q];
    }
    while (have) {
        u32 g8[8];
#pragma unroll
        for (int q = 0; q < 8; q++) g8[q] = pr[q];
        int en = e + 8;
        bool haven = (en + 8 <= end);
        if (haven) {
#pragma unroll
            for (int q = 0; q < 8; q++) pr[q] = ep4[en + q];
        }
#pragma unroll
        for (int q = 0; q < 8; q++) {
            u16x8 u = *(const u16x8*)&in[(size_t)(g8[q] & SRC_MASK) * H + l * 8];
            float wt = dnode * rsqrtf(1.0f + (float)(g8[q] >> DEG_SHIFT));
#pragma unroll
            for (int r = 0; r < 8; r++) a[r] += bf2f(u[r]) * wt;
        }
        e = en; have = haven;
    }
    for (; e < end; e++) {
        u32 pe = ep4[e];
        float wt = dnode * rsqrtf(1.0f + (float)(pe >> DEG_SHIFT));
        u16x8 u = *(const u16x8*)&in[(size_t)(pe & SRC_MASK) * H + l * 8];
#pragma unroll
        for (int r = 0; r < 8; r++) a[r] += bf2f(u[r]) * wt;
    }
    u16x8 us = *(const u16x8*)&in[(size_t)node * H + l * 8];
    float dd = dnode * dnode;
    f32x4 lo4, hi4;
#pragma unroll
    for (int r = 0; r < 4; r++) lo4[r] = a[r] + bf2f(us[r]) * dd;
#pragma unroll
    for (int r = 0; r < 4; r++) hi4[r] = a[r + 4] + bf2f(us[r + 4]) * dd;
    *(f32x4*)&pacc[hw][l * 8] = lo4;
    *(f32x4*)&pacc[hw][l * 8 + 4] = hi4;
    if (l == 0) gslot[hw] = batch[node] - gbase;
    __syncthreads();

    // reduce 8 node-rows by graph slot, flush with global f32 atomics
    int smax = gslot[7];          // batch[perm] sorted -> slots non-decreasing
    float v[8];
#pragma unroll
    for (int q = 0; q < 8; q++) v[q] = pacc[q][tid];
    for (int s = 0; s <= smax; s++) {
        float acc = 0.f;
#pragma unroll
        for (int q = 0; q < 8; q++)
            if (gslot[q] == s) acc += v[q];
        atomicAdd(&poolacc[(size_t)(gbase + s) * H + tid], acc);
    }
}

// ---------------- pool finalize: divide by counts, hi/lo bf16 split ----------------
__global__ __launch_bounds__(256) void pool_finalize2(
        const float* __restrict__ poolacc, const int* __restrict__ goff,
        u16* __restrict__ phi, u16* __restrict__ plo) {
    int g = blockIdx.x, t = threadIdx.x;
    float c = (float)(goff[g + 1] - goff[g]);
    float acc = poolacc[(size_t)g * H + t] / fmaxf(c, 1.f);
    u16 hv = f2bf(acc);
    phi[g * H + t] = hv;
    plo[g * H + t] = f2bf(acc - bf2f(hv));
}

// ---------------- MFMA GEMM with bias(+relu) epilogue (node layers) ----------------
template<int K, bool RELU>
__global__ __launch_bounds__(256) void gemm_bias(
        const u16* __restrict__ A,
        const u16* __restrict__ Bhi, const u16* __restrict__ Blo,
        const float* __restrict__ bias, u16* __restrict__ C, int M) {
    __shared__ __align__(16) u16 sA[128 * 40];
    __shared__ __align__(16) u16 sB[2 * 128 * 40];
    const int tid = threadIdx.x;
    const int w = tid >> 6, l = tid & 63;
    const int wm = (w & 1) * 64, wn = (w >> 1) * 64;
    const int bm = blockIdx.x * 128, bn = blockIdx.y * 128;
    const int srow = tid >> 2;
    const int schunk = (tid & 3) * 8;
    const int lr = l & 15, lg = (l >> 4) * 8;

    f32x4 acc[4][4] = {};

    for (int k0 = 0; k0 < K; k0 += 32) {
        {
            int r0 = bm + srow, r1 = bm + srow + 64;
            u16x8 v0 = {}, v1 = {};
            if (r0 < M) v0 = *(const u16x8*)&A[(size_t)r0 * K + k0 + schunk];
            if (r1 < M) v1 = *(const u16x8*)&A[(size_t)r1 * K + k0 + schunk];
            *(u16x8*)&sA[srow * 40 + schunk] = v0;
            *(u16x8*)&sA[(srow + 64) * 40 + schunk] = v1;
        }
        {
            int n0 = bn + srow, n1 = bn + srow + 64;
            *(u16x8*)&sB[srow * 40 + schunk] = *(const u16x8*)&Bhi[(size_t)n0 * K + k0 + schunk];
            *(u16x8*)&sB[(srow + 64) * 40 + schunk] = *(const u16x8*)&Bhi[(size_t)n1 * K + k0 + schunk];
            *(u16x8*)&sB[128 * 40 + srow * 40 + schunk] = *(const u16x8*)&Blo[(size_t)n0 * K + k0 + schunk];
            *(u16x8*)&sB[128 * 40 + (srow + 64) * 40 + schunk] = *(const u16x8*)&Blo[(size_t)n1 * K + k0 + schunk];
        }
        __syncthreads();

        s16x8 af[4], bh[4], bl[4];
#pragma unroll
        for (int i = 0; i < 4; i++)
            af[i] = __builtin_bit_cast(s16x8, *(const u16x8*)&sA[(wm + i * 16 + lr) * 40 + lg]);
#pragma unroll
        for (int j = 0; j < 4; j++) {
            bh[j] = __builtin_bit_cast(s16x8, *(const u16x8*)&sB[(wn + j * 16 + lr) * 40 + lg]);
            bl[j] = __builtin_bit_cast(s16x8, *(const u16x8*)&sB[128 * 40 + (wn + j * 16 + lr) * 40 + lg]);
        }
#pragma unroll
        for (int i = 0; i < 4; i++) {
#pragma unroll
            for (int j = 0; j < 4; j++) {
                acc[i][j] = __builtin_amdgcn_mfma_f32_16x16x32_bf16(af[i], bh[j], acc[i][j], 0, 0, 0);
                acc[i][j] = __builtin_amdgcn_mfma_f32_16x16x32_bf16(af[i], bl[j], acc[i][j], 0, 0, 0);
            }
        }
        __syncthreads();
    }

    float bcol[4];
#pragma unroll
    for (int j = 0; j < 4; j++) bcol[j] = bias[bn + wn + j * 16 + lr];

    const int lq = (l >> 4) * 4;
#pragma unroll
    for (int i = 0; i < 4; i++) {
#pragma unroll
        for (int r0 = 0; r0 < 4; r0++) {
            int row = bm + wm + i * 16 + lq + r0;
            if (row < M) {
#pragma unroll
                for (int j = 0; j < 4; j++) {
                    float v = acc[i][j][r0] + bcol[j];
                    if (RELU) v = fmaxf(v, 0.f);
                    C[(size_t)row * H + bn + wn + j * 16 + lr] = f2bf(v);
                }
            }
        }
    }
}

// ---------------- split-precision MFMA GEMM (MLP tail) ----------------
template<int K, int NW, bool RELU, bool F32OUT>
__global__ __launch_bounds__(256) void gemm_split(
        const u16* __restrict__ Ahi, const u16* __restrict__ Alo,
        const u16* __restrict__ Bhi, const u16* __restrict__ Blo,
        const float* __restrict__ bias,
        u16* __restrict__ Chi, u16* __restrict__ Clo, float* __restrict__ Cf,
        int M) {
    __shared__ __align__(16) u16 sA[2 * 128 * 40];
    __shared__ __align__(16) u16 sB[2 * 128 * 40];
    const int tid = threadIdx.x;
    const int w = tid >> 6, l = tid & 63;
    const int wm = (w & 1) * 64, wn = (w >> 1) * 64;
    const int bm = blockIdx.x * 128, bn = blockIdx.y * 128;
    const int srow = tid >> 2;
    const int schunk = (tid & 3) * 8;
    const int lr = l & 15, lg = (l >> 4) * 8;

    f32x4 acc[4][4] = {};

    for (int k0 = 0; k0 < K; k0 += 32) {
        {
            int r0 = bm + srow, r1 = bm + srow + 64;
            u16x8 v0 = {}, v1 = {}, w0 = {}, w1 = {};
            if (r0 < M) {
                v0 = *(const u16x8*)&Ahi[(size_t)r0 * K + k0 + schunk];
                w0 = *(const u16x8*)&Alo[(size_t)r0 * K + k0 + schunk];
            }
            if (r1 < M) {
                v1 = *(const u16x8*)&Ahi[(size_t)r1 * K + k0 + schunk];
                w1 = *(const u16x8*)&Alo[(size_t)r1 * K + k0 + schunk];
            }
            *(u16x8*)&sA[srow * 40 + schunk] = v0;
            *(u16x8*)&sA[(srow + 64) * 40 + schunk] = v1;
            *(u16x8*)&sA[128 * 40 + srow * 40 + schunk] = w0;
            *(u16x8*)&sA[128 * 40 + (srow + 64) * 40 + schunk] = w1;
        }
        {
            int n0 = bn + srow, n1 = bn + srow + 64;
            *(u16x8*)&sB[srow * 40 + schunk] = *(const u16x8*)&Bhi[(size_t)n0 * K + k0 + schunk];
            *(u16x8*)&sB[(srow + 64) * 40 + schunk] = *(const u16x8*)&Bhi[(size_t)n1 * K + k0 + schunk];
            *(u16x8*)&sB[128 * 40 + srow * 40 + schunk] = *(const u16x8*)&Blo[(size_t)n0 * K + k0 + schunk];
            *(u16x8*)&sB[128 * 40 + (srow + 64) * 40 + schunk] = *(const u16x8*)&Blo[(size_t)n1 * K + k0 + schunk];
        }
        __syncthreads();

        s16x8 af[4], al[4], bh[4], bl[4];
#pragma unroll
        for (int i = 0; i < 4; i++) {
            af[i] = __builtin_bit_cast(s16x8, *(const u16x8*)&sA[(wm + i * 16 + lr) * 40 + lg]);
            al[i] = __builtin_bit_cast(s16x8, *(const u16x8*)&sA[128 * 40 + (wm + i * 16 + lr) * 40 + lg]);
        }
#pragma unroll
        for (int j = 0; j < 4; j++) {
            bh[j] = __builtin_bit_cast(s16x8, *(const u16x8*)&sB[(wn + j * 16 + lr) * 40 + lg]);
            bl[j] = __builtin_bit_cast(s16x8, *(const u16x8*)&sB[128 * 40 + (wn + j * 16 + lr) * 40 + lg]);
        }
#pragma unroll
        for (int i = 0; i < 4; i++) {
#pragma unroll
            for (int j = 0; j < 4; j++) {
                acc[i][j] = __builtin_amdgcn_mfma_f32_16x16x32_bf16(af[i], bh[j], acc[i][j], 0, 0, 0);
                acc[i][j] = __builtin_amdgcn_mfma_f32_16x16x32_bf16(af[i], bl[j], acc[i][j], 0, 0, 0);
                acc[i][j] = __builtin_amdgcn_mfma_f32_16x16x32_bf16(al[i], bh[j], acc[i][j], 0, 0, 0);
            }
        }
        __syncthreads();
    }

    float bcol[4];
#pragma unroll
    for (int j = 0; j < 4; j++) bcol[j] = bias[bn + wn + j * 16 + lr];

    const int lq = (l >> 4) * 4;
#pragma unroll
    for (int i = 0; i < 4; i++) {
#pragma unroll
        for (int r0 = 0; r0 < 4; r0++) {
            int row = bm + wm + i * 16 + lq + r0;
            if (row < M) {
#pragma unroll
                for (int j = 0; j < 4; j++) {
                    float v = acc[i][j][r0] + bcol[j];
                    if (RELU) v = fmaxf(v, 0.f);
                    size_t idx = (size_t)row * NW + bn + wn + j * 16 + lr;
                    if (F32OUT) {
                        Cf[idx] = v;
                    } else {
                        u16 hv = f2bf(v);
                        Chi[idx] = hv;
                        Clo[idx] = f2bf(v - bf2f(hv));
                    }
                }
            }
        }
    }
}

// ---------------- launch ----------------
extern "C" void kernel_launch(void* const* d_in, const int* in_sizes, int n_in,
                              void* d_out, int out_size, void* d_ws, size_t ws_size,
                              hipStream_t stream) {
    const float* x   = (const float*)d_in[0];
    const int*   src = (const int*)d_in[1];
    const int*   dst = (const int*)d_in[2];
    const int*   bat = (const int*)d_in[3];
    const float* W1  = (const float*)d_in[4];  const float* b1  = (const float*)d_in[5];
    const float* W2  = (const float*)d_in[6];  const float* b2  = (const float*)d_in[7];
    const float* W3  = (const float*)d_in[8];  const float* b3  = (const float*)d_in[9];
    const float* Wm1 = (const float*)d_in[10]; const float* bm1 = (const float*)d_in[11];
    const float* Wm2 = (const float*)d_in[12]; const float* bm2 = (const float*)d_in[13];
    float* out = (float*)d_out;

    char* p = (char*)d_ws;
    auto carve = [&](size_t bytes) -> void* {
        void* r = (void*)p;
        p += (bytes + 511) & ~(size_t)511;
        return r;
    };
    u16*   x_bf    = (u16*)  carve((size_t)N_NODES * F_IN * 2);
    u16*   aggX    = (u16*)  carve((size_t)N_NODES * F_IN * 2);
    u16*   bufA    = (u16*)  carve((size_t)N_NODES * H * 2);
    u16*   bufB    = (u16*)  carve((size_t)N_NODES * H * 2);
    float* dinv    = (float*)carve((size_t)N_NODES * 4);
    int*   degc    = (int*)  carve((size_t)N_NODES * 4);
    int*   rowp    = (int*)  carve((size_t)(N_NODES + 1) * 4);
    int*   cur     = (int*)  carve((size_t)N_NODES * 4);
    u32*   ep4     = (u32*)  carve((size_t)N_EDGES * 4);
    u32*   pack    = (u32*)  carve((size_t)N_NODES * 4);
    int*   partial = (int*)  carve(4096);
    int*   goff    = (int*)  carve((size_t)(G_GR + 1) * 4);
    int*   khist   = (int*)  carve((size_t)NKEYS * 4);
    int*   kcur    = (int*)  carve((size_t)NKEYS * 4);
    int*   perm    = (int*)  carve((size_t)N_NODES * 4);
    u16*   Wt1_hi  = (u16*)  carve((size_t)F_IN * H * 2);
    u16*   Wt1_lo  = (u16*)  carve((size_t)F_IN * H * 2);
    u16*   Wt2_hi  = (u16*)  carve((size_t)H * H * 2);
    u16*   Wt2_lo  = (u16*)  carve((size_t)H * H * 2);
    u16*   Wt3_hi  = (u16*)  carve((size_t)H * H * 2);
    u16*   Wt3_lo  = (u16*)  carve((size_t)H * H * 2);
    u16*   Wm1t_hi = (u16*)  carve((size_t)H * NHID * 2);
    u16*   Wm1t_lo = (u16*)  carve((size_t)H * NHID * 2);
    u16*   Wm2t_hi = (u16*)  carve((size_t)NHID * NOUT * 2);
    u16*   Wm2t_lo = (u16*)  carve((size_t)NHID * NOUT * 2);
    u16*   p_hi    = (u16*)  carve((size_t)G_GR * H * 2);
    u16*   p_lo    = (u16*)  carve((size_t)G_GR * H * 2);
    u16*   y_hi    = (u16*)  carve((size_t)G_GR * H * 2);
    u16*   y_lo    = (u16*)  carve((size_t)G_GR * H * 2);
    u16*   hd_hi   = (u16*)  carve((size_t)G_GR * NHID * 2);
    u16*   hd_lo   = (u16*)  carve((size_t)G_GR * NHID * 2);
    float* poolacc = (float*)carve((size_t)G_GR * H * 4);

    const int NB = (N_NODES + 255) / 256;

    hipMemsetAsync(degc, 0, (size_t)N_NODES * 4, stream);
    hipMemsetAsync(poolacc, 0, (size_t)G_GR * H * 4, stream);
    hipMemsetAsync(khist, 0, (size_t)NKEYS * 4, stream);
    prep_head<<<HEAD_BLKS, 256, 0, stream>>>(dst, degc,
                                             W1, Wt1_hi, Wt1_lo,
                                             W2, Wt2_hi, Wt2_lo,
                                             W3, Wt3_hi, Wt3_lo,
                                             Wm1, Wm1t_hi, Wm1t_lo,
                                             Wm2, Wm2t_hi, Wm2t_lo, bat, goff);
    scan_partial<<<NB, 256, 0, stream>>>(degc, partial);
    scan_offsets<<<1, 512, 0, stream>>>(partial, NB, rowp);
    scan_final_dinv<<<NB, 256, 0, stream>>>(degc, partial, rowp, cur, dinv, pack, bat, khist);
    // node sort by (batch, deg) for degree-uniform wave packing
    scan_hist<<<1, 256, 0, stream>>>(khist, kcur);
    perm_scatter<<<NB, 256, 0, stream>>>(degc, bat, kcur, perm);
    // scatter (packed 4B entries) + split_x freight
    scatter_splitx<<<CD_BLKS + SPX_BLKS, 256, 0, stream>>>(src, dst, pack, cur, ep4, x, x_bf);

    dim3 ggrid((N_NODES + 127) / 128, 2);

    // layer 1: aggregate-first (256B rows), then transform+bias+relu
    gcn_agg128<<<N_NODES / 16, 256, 0, stream>>>(x_bf, rowp, ep4, dinv, perm, aggX);
    gemm_bias<F_IN, true><<<ggrid, 256, 0, stream>>>(aggX, Wt1_hi, Wt1_lo, b1, bufA, N_NODES);
    // layer 2
    gcn_agg256<<<N_NODES / 8, 256, 0, stream>>>(bufA, rowp, ep4, dinv, perm, bufB);
    gemm_bias<H, true><<<ggrid, 256, 0, stream>>>(bufB, Wt2_hi, Wt2_lo, b2, bufA, N_NODES);
    // layer 3 + pool fused (gather form): per-node f32 row -> LDS -> per-graph atomic flush
    gcn_agg_pool<<<N_NODES / 8, 256, 0, stream>>>(bufA, rowp, ep4, dinv, perm, bat, poolacc);
    pool_finalize2<<<G_GR, 256, 0, stream>>>(poolacc, goff, p_hi, p_lo);

    // tail: y=pW3+b3 -> hidden=relu(yWm1+bm1) -> out=hidden Wm2+bm2
    dim3 g3(2, 2), gm1(2, 4), gm2(2, 2);
    gemm_split<H, H, false, false><<<g3, 256, 0, stream>>>(
        p_hi, p_lo, Wt3_hi, Wt3_lo, b3, y_hi, y_lo, nullptr, G_GR);
    gemm_split<H, NHID, true, false><<<gm1, 256, 0, stream>>>(
        y_hi, y_lo, Wm1t_hi, Wm1t_lo, bm1, hd_hi, hd_lo, nullptr, G_GR);
    gemm_split<NHID, NOUT, false, true><<<gm2, 256, 0, stream>>>(
        hd_hi, hd_lo, Wm2t_hi, Wm2t_lo, bm2, nullptr, nullptr, out, G_GR);
}

// Round 5
// 696.437 us; speedup vs baseline: 1.0170x; 1.0170x over previous
//
#include <hip/hip_runtime.h>
#include <hip/hip_bf16.h>

#define N_NODES 100000
#define N_EDGES 1600000
#define F_IN    128
#define H       256
#define NHID    512
#define NOUT    256
#define G_GR    256

typedef unsigned short u16;
typedef unsigned int u32;
typedef __attribute__((ext_vector_type(8))) short s16x8;
typedef __attribute__((ext_vector_type(8))) unsigned short u16x8;
typedef __attribute__((ext_vector_type(4))) float f32x4;

// edge entry encoding: (src:17b | indeg_src:15b). wt recomputed as
// dinv[dst]*rsqrtf(1+deg) — bit-identical to storing the product.
#define SRC_MASK 0x1FFFFu
#define DEG_SHIFT 17

__device__ __forceinline__ float bf2f(u16 u) {
    union { unsigned int i; float f; } v; v.i = ((unsigned int)u) << 16; return v.f;
}
__device__ __forceinline__ u16 f2bf(float f) {
    union { float f; unsigned int i; } v; v.f = f;
    unsigned int x = v.i;
    x += 0x7fffu + ((x >> 16) & 1u);
    return (u16)(x >> 16);
}

// ---------------- head: count_deg (atomics) + LDS-tiled weight transposes + goff -----
#define CD_BLKS   1563                        // 4 strided edges/thread (R8 known-good form)
#define SPX_BLKS  ((N_NODES * F_IN) / 1024)   // 12500 — carried by scatter kernel
#define T1_TILES  ((F_IN / 64) * (H / 64))    // 8
#define T2_TILES  ((H / 64) * (H / 64))       // 16
#define T3_TILES  ((H / 64) * (H / 64))       // 16
#define TM1_TILES ((H / 64) * (NHID / 64))    // 32
#define TM2_TILES ((NHID / 64) * (NOUT / 64)) // 32
#define HEAD_BLKS (CD_BLKS + T1_TILES + T2_TILES + T3_TILES + TM1_TILES + TM2_TILES + 2)

// 64x64 tile transpose via padded LDS: coalesced f32 reads, coalesced 2B hi/lo stores.
__device__ __forceinline__ void transpose_tile(float (*tile)[65],
        const float* __restrict__ W, u16* __restrict__ thi, u16* __restrict__ tlo,
        int K, int N, int tileIdx) {
    const int ntn = N >> 6;
    const int tk = tileIdx / ntn, tn = tileIdx - tk * ntn;
    const int t = threadIdx.x;
    const int c = t & 63, r4 = t >> 6;
#pragma unroll
    for (int i = 0; i < 64; i += 4)
        tile[r4 + i][c] = W[(size_t)(tk * 64 + r4 + i) * N + tn * 64 + c];
    __syncthreads();
#pragma unroll
    for (int i = 0; i < 64; i += 4) {
        int n = tn * 64 + r4 + i, k = tk * 64 + c;
        float f = tile[c][r4 + i];
        u16 h = f2bf(f);
        thi[(size_t)n * K + k] = h;
        tlo[(size_t)n * K + k] = f2bf(f - bf2f(h));
    }
}

__global__ __launch_bounds__(256) void prep_head(
        const int* __restrict__ dst, int* __restrict__ degc,
        const float* __restrict__ W1, u16* __restrict__ t1h, u16* __restrict__ t1l,
        const float* __restrict__ W2, u16* __restrict__ t2h, u16* __restrict__ t2l,
        const float* __restrict__ W3, u16* __restrict__ t3h, u16* __restrict__ t3l,
        const float* __restrict__ Wm1, u16* __restrict__ tm1h, u16* __restrict__ tm1l,
        const float* __restrict__ Wm2, u16* __restrict__ tm2h, u16* __restrict__ tm2l,
        const int* __restrict__ batch, int* __restrict__ goff) {
    __shared__ float tile[64][65];
    int bid = blockIdx.x;
    if (bid < CD_BLKS) {
        int base = bid * 1024 + threadIdx.x;
#pragma unroll
        for (int q = 0; q < 4; q++) {
            int e = base + q * 256;
            if (e < N_EDGES) atomicAdd(&degc[dst[e]], 1);
        }
        return;
    }
    bid -= CD_BLKS;
    if (bid < T1_TILES) { transpose_tile(tile, W1, t1h, t1l, F_IN, H, bid); return; }
    bid -= T1_TILES;
    if (bid < T2_TILES) { transpose_tile(tile, W2, t2h, t2l, H, H, bid); return; }
    bid -= T2_TILES;
    if (bid < T3_TILES) { transpose_tile(tile, W3, t3h, t3l, H, H, bid); return; }
    bid -= T3_TILES;
    if (bid < TM1_TILES) { transpose_tile(tile, Wm1, tm1h, tm1l, H, NHID, bid); return; }
    bid -= TM1_TILES;
    if (bid < TM2_TILES) { transpose_tile(tile, Wm2, tm2h, tm2l, NHID, NOUT, bid); return; }
    bid -= TM2_TILES;
    {
        int g = bid * 256 + threadIdx.x;
        if (g > G_GR) return;
        int lo = 0, hi = N_NODES;
        while (lo < hi) {
            int mid = (lo + hi) >> 1;
            if (batch[mid] < g) lo = mid + 1; else hi = mid;
        }
        goff[g] = lo;
    }
}

// ---------------- scan (CSR rowp) ----------------
__global__ void scan_partial(const int* __restrict__ cnt, int* __restrict__ partial) {
    __shared__ int s[256];
    int t = threadIdx.x;
    int i = blockIdx.x * 256 + t;
    int v = (i < N_NODES) ? cnt[i] : 0;
    s[t] = v; __syncthreads();
    for (int off = 128; off > 0; off >>= 1) {
        if (t < off) s[t] += s[t + off];
        __syncthreads();
    }
    if (t == 0) partial[blockIdx.x] = s[0];
}

__global__ void scan_offsets(int* __restrict__ partial, int nb, int* __restrict__ rowp) {
    __shared__ int s[512];
    int t = threadIdx.x;
    int orig = (t < nb) ? partial[t] : 0;
    s[t] = orig; __syncthreads();
    for (int off = 1; off < 512; off <<= 1) {
        int u = (t >= off) ? s[t - off] : 0;
        __syncthreads();
        s[t] += u;
        __syncthreads();
    }
    if (t < nb) partial[t] = s[t] - orig;
    if (t == 0) rowp[N_NODES] = N_EDGES;
}

// also zeros poolacc (first 256 blocks) — replaces a hipMemsetAsync dispatch
__global__ void scan_final_dinv(const int* __restrict__ cnt, const int* __restrict__ partial,
                                int* __restrict__ rowp, int* __restrict__ cur,
                                float* __restrict__ dinv, u32* __restrict__ pack,
                                float* __restrict__ poolacc) {
    __shared__ int s[256];
    int t = threadIdx.x;
    int i = blockIdx.x * 256 + t;
    if (i < G_GR * H) poolacc[i] = 0.f;
    int v = (i < N_NODES) ? cnt[i] : 0;
    s[t] = v; __syncthreads();
    for (int off = 1; off < 256; off <<= 1) {
        int u = (t >= off) ? s[t - off] : 0;
        __syncthreads();
        s[t] += u;
        __syncthreads();
    }
    if (i < N_NODES) {
        int r = partial[blockIdx.x] + s[t] - v;
        rowp[i] = r;
        cur[i] = r;
        dinv[i] = rsqrtf(1.0f + (float)v);
        pack[i] = (u32)i | ((u32)v << DEG_SHIFT);
    }
}

// ---------------- scatter (packed 4B entries) + split_x streaming freight ----------------
__global__ __launch_bounds__(256) void scatter_splitx(
        const int* __restrict__ src, const int* __restrict__ dst,
        const u32* __restrict__ pack, int* __restrict__ cur,
        u32* __restrict__ ep4,
        const float* __restrict__ x, u16* __restrict__ x_bf) {
    int bid = blockIdx.x;
    if (bid < CD_BLKS) {
        int base = bid * 1024 + threadIdx.x;
#pragma unroll
        for (int q = 0; q < 4; q++) {
            int e = base + q * 256;
            if (e < N_EDGES) {
                int d = dst[e];
                int s = src[e];
                u32 pk = pack[s];
                int pos = atomicAdd(&cur[d], 1);
                ep4[pos] = pk;
            }
        }
        return;
    }
    bid -= CD_BLKS;
    {   // split_x: 4 floats/thread, 12500 blocks
        int idx = bid * 256 + threadIdx.x;
        float4 f = *(const float4*)&x[(size_t)idx * 4];
        ushort4 o;
        o.x = f2bf(f.x); o.y = f2bf(f.y); o.z = f2bf(f.z); o.w = f2bf(f.w);
        *(ushort4*)&x_bf[(size_t)idx * 4] = o;
    }
}

// ---------------- aggregation: half-wave (32 lanes x ushort8) per node, H=256 ----------------
__global__ __launch_bounds__(256) void gcn_agg256(
        const u16* __restrict__ in, const int* __restrict__ rowp,
        const u32* __restrict__ ep4, const float* __restrict__ dinv,
        u16* __restrict__ outp) {
    int node = blockIdx.x * 8 + (threadIdx.x >> 5);
    int l = threadIdx.x & 31;
    int beg = rowp[node], end = rowp[node + 1];
    float dnode = dinv[node];
    float a[8] = {};
    int e = beg;
    u32 pr[8];
    bool have = (e + 8 <= end);
    if (have) {
#pragma unroll
        for (int q = 0; q < 8; q++) pr[q] = ep4[e + q];
    }
    while (have) {
        u32 g8[8];
#pragma unroll
        for (int q = 0; q < 8; q++) g8[q] = pr[q];
        int en = e + 8;
        bool haven = (en + 8 <= end);
        if (haven) {
#pragma unroll
            for (int q = 0; q < 8; q++) pr[q] = ep4[en + q];
        }
#pragma unroll
        for (int q = 0; q < 8; q++) {
            u16x8 u = *(const u16x8*)&in[(size_t)(g8[q] & SRC_MASK) * H + l * 8];
            float wt = dnode * rsqrtf(1.0f + (float)(g8[q] >> DEG_SHIFT));
#pragma unroll
            for (int r = 0; r < 8; r++) a[r] += bf2f(u[r]) * wt;
        }
        e = en; have = haven;
    }
    for (; e < end; e++) {
        u32 pe = ep4[e];
        float wt = dnode * rsqrtf(1.0f + (float)(pe >> DEG_SHIFT));
        u16x8 u = *(const u16x8*)&in[(size_t)(pe & SRC_MASK) * H + l * 8];
#pragma unroll
        for (int r = 0; r < 8; r++) a[r] += bf2f(u[r]) * wt;
    }
    u16x8 us = *(const u16x8*)&in[(size_t)node * H + l * 8];
    float dd = dnode * dnode;
    u16x8 o;
#pragma unroll
    for (int r = 0; r < 8; r++) o[r] = f2bf(a[r] + bf2f(us[r]) * dd);
    *(u16x8*)&outp[(size_t)node * H + l * 8] = o;
}

// ---------------- aggregation: quarter-wave (16 lanes x ushort8) per node, F=128 ----------------
__global__ __launch_bounds__(256) void gcn_agg128(
        const u16* __restrict__ in, const int* __restrict__ rowp,
        const u32* __restrict__ ep4, const float* __restrict__ dinv,
        u16* __restrict__ outp) {
    int node = blockIdx.x * 16 + (threadIdx.x >> 4);
    int l = threadIdx.x & 15;
    int beg = rowp[node], end = rowp[node + 1];
    float dnode = dinv[node];
    float a[8] = {};
    int e = beg;
    u32 pr[8];
    bool have = (e + 8 <= end);
    if (have) {
#pragma unroll
        for (int q = 0; q < 8; q++) pr[q] = ep4[e + q];
    }
    while (have) {
        u32 g8[8];
#pragma unroll
        for (int q = 0; q < 8; q++) g8[q] = pr[q];
        int en = e + 8;
        bool haven = (en + 8 <= end);
        if (haven) {
#pragma unroll
            for (int q = 0; q < 8; q++) pr[q] = ep4[en + q];
        }
#pragma unroll
        for (int q = 0; q < 8; q++) {
            u16x8 u = *(const u16x8*)&in[(size_t)(g8[q] & SRC_MASK) * F_IN + l * 8];
            float wt = dnode * rsqrtf(1.0f + (float)(g8[q] >> DEG_SHIFT));
#pragma unroll
            for (int r = 0; r < 8; r++) a[r] += bf2f(u[r]) * wt;
        }
        e = en; have = haven;
    }
    for (; e < end; e++) {
        u32 pe = ep4[e];
        float wt = dnode * rsqrtf(1.0f + (float)(pe >> DEG_SHIFT));
        u16x8 u = *(const u16x8*)&in[(size_t)(pe & SRC_MASK) * F_IN + l * 8];
#pragma unroll
        for (int r = 0; r < 8; r++) a[r] += bf2f(u[r]) * wt;
    }
    u16x8 us = *(const u16x8*)&in[(size_t)node * F_IN + l * 8];
    float dd = dnode * dnode;
    u16x8 o;
#pragma unroll
    for (int r = 0; r < 8; r++) o[r] = f2bf(a[r] + bf2f(us[r]) * dd);
    *(u16x8*)&outp[(size_t)node * F_IN + l * 8] = o;
}

// ---------------- layer-3 fused agg+pool: gather form, no per-node output ----------------
__global__ __launch_bounds__(256) void gcn_agg_pool(
        const u16* __restrict__ in, const int* __restrict__ rowp,
        const u32* __restrict__ ep4, const float* __restrict__ dinv,
        const int* __restrict__ batch, float* __restrict__ poolacc) {
    __shared__ __align__(16) float pacc[8][H];
    __shared__ int gslot[8];
    const int tid = threadIdx.x;
    const int hw = tid >> 5;
    const int l = tid & 31;
    const int node = blockIdx.x * 8 + hw;
    const int gbase = batch[blockIdx.x * 8];

    int beg = rowp[node], end = rowp[node + 1];
    float dnode = dinv[node];
    float a[8] = {};
    int e = beg;
    u32 pr[8];
    bool have = (e + 8 <= end);
    if (have) {
#pragma unroll
        for (int q = 0; q < 8; q++) pr[q] = ep4[e + q];
    }
    while (have) {
        u32 g8[8];
#pragma unroll
        for (int q = 0; q < 8; q++) g8[q] = pr[q];
        int en = e + 8;
        bool haven = (en + 8 <= end);
        if (haven) {
#pragma unroll
            for (int q = 0; q < 8; q++) pr[q] = ep4[en + q];
        }
#pragma unroll
        for (int q = 0; q < 8; q++) {
            u16x8 u = *(const u16x8*)&in[(size_t)(g8[q] & SRC_MASK) * H + l * 8];
            float wt = dnode * rsqrtf(1.0f + (float)(g8[q] >> DEG_SHIFT));
#pragma unroll
            for (int r = 0; r < 8; r++) a[r] += bf2f(u[r]) * wt;
        }
        e = en; have = haven;
    }
    for (; e < end; e++) {
        u32 pe = ep4[e];
        float wt = dnode * rsqrtf(1.0f + (float)(pe >> DEG_SHIFT));
        u16x8 u = *(const u16x8*)&in[(size_t)(pe & SRC_MASK) * H + l * 8];
#pragma unroll
        for (int r = 0; r < 8; r++) a[r] += bf2f(u[r]) * wt;
    }
    u16x8 us = *(const u16x8*)&in[(size_t)node * H + l * 8];
    float dd = dnode * dnode;
    f32x4 lo4, hi4;
#pragma unroll
    for (int r = 0; r < 4; r++) lo4[r] = a[r] + bf2f(us[r]) * dd;
#pragma unroll
    for (int r = 0; r < 4; r++) hi4[r] = a[r + 4] + bf2f(us[r + 4]) * dd;
    *(f32x4*)&pacc[hw][l * 8] = lo4;
    *(f32x4*)&pacc[hw][l * 8 + 4] = hi4;
    if (l == 0) gslot[hw] = batch[node] - gbase;
    __syncthreads();

    // reduce 8 node-rows by graph slot, flush with global f32 atomics
    int smax = gslot[7];          // batch sorted -> slots non-decreasing
    float v[8];
#pragma unroll
    for (int q = 0; q < 8; q++) v[q] = pacc[q][tid];
    for (int s = 0; s <= smax; s++) {
        float acc = 0.f;
#pragma unroll
        for (int q = 0; q < 8; q++)
            if (gslot[q] == s) acc += v[q];
        atomicAdd(&poolacc[(size_t)(gbase + s) * H + tid], acc);
    }
}

// ---------------- MFMA GEMM with bias(+relu) epilogue (node layers) ----------------
template<int K, bool RELU>
__global__ __launch_bounds__(256) void gemm_bias(
        const u16* __restrict__ A,
        const u16* __restrict__ Bhi, const u16* __restrict__ Blo,
        const float* __restrict__ bias, u16* __restrict__ C, int M) {
    __shared__ __align__(16) u16 sA[128 * 40];
    __shared__ __align__(16) u16 sB[2 * 128 * 40];
    const int tid = threadIdx.x;
    const int w = tid >> 6, l = tid & 63;
    const int wm = (w & 1) * 64, wn = (w >> 1) * 64;
    const int bm = blockIdx.x * 128, bn = blockIdx.y * 128;
    const int srow = tid >> 2;
    const int schunk = (tid & 3) * 8;
    const int lr = l & 15, lg = (l >> 4) * 8;

    f32x4 acc[4][4] = {};

    for (int k0 = 0; k0 < K; k0 += 32) {
        {
            int r0 = bm + srow, r1 = bm + srow + 64;
            u16x8 v0 = {}, v1 = {};
            if (r0 < M) v0 = *(const u16x8*)&A[(size_t)r0 * K + k0 + schunk];
            if (r1 < M) v1 = *(const u16x8*)&A[(size_t)r1 * K + k0 + schunk];
            *(u16x8*)&sA[srow * 40 + schunk] = v0;
            *(u16x8*)&sA[(srow + 64) * 40 + schunk] = v1;
        }
        {
            int n0 = bn + srow, n1 = bn + srow + 64;
            *(u16x8*)&sB[srow * 40 + schunk] = *(const u16x8*)&Bhi[(size_t)n0 * K + k0 + schunk];
            *(u16x8*)&sB[(srow + 64) * 40 + schunk] = *(const u16x8*)&Bhi[(size_t)n1 * K + k0 + schunk];
            *(u16x8*)&sB[128 * 40 + srow * 40 + schunk] = *(const u16x8*)&Blo[(size_t)n0 * K + k0 + schunk];
            *(u16x8*)&sB[128 * 40 + (srow + 64) * 40 + schunk] = *(const u16x8*)&Blo[(size_t)n1 * K + k0 + schunk];
        }
        __syncthreads();

        s16x8 af[4], bh[4], bl[4];
#pragma unroll
        for (int i = 0; i < 4; i++)
            af[i] = __builtin_bit_cast(s16x8, *(const u16x8*)&sA[(wm + i * 16 + lr) * 40 + lg]);
#pragma unroll
        for (int j = 0; j < 4; j++) {
            bh[j] = __builtin_bit_cast(s16x8, *(const u16x8*)&sB[(wn + j * 16 + lr) * 40 + lg]);
            bl[j] = __builtin_bit_cast(s16x8, *(const u16x8*)&sB[128 * 40 + (wn + j * 16 + lr) * 40 + lg]);
        }
#pragma unroll
        for (int i = 0; i < 4; i++) {
#pragma unroll
            for (int j = 0; j < 4; j++) {
                acc[i][j] = __builtin_amdgcn_mfma_f32_16x16x32_bf16(af[i], bh[j], acc[i][j], 0, 0, 0);
                acc[i][j] = __builtin_amdgcn_mfma_f32_16x16x32_bf16(af[i], bl[j], acc[i][j], 0, 0, 0);
            }
        }
        __syncthreads();
    }

    float bcol[4];
#pragma unroll
    for (int j = 0; j < 4; j++) bcol[j] = bias[bn + wn + j * 16 + lr];

    const int lq = (l >> 4) * 4;
#pragma unroll
    for (int i = 0; i < 4; i++) {
#pragma unroll
        for (int r0 = 0; r0 < 4; r0++) {
            int row = bm + wm + i * 16 + lq + r0;
            if (row < M) {
#pragma unroll
                for (int j = 0; j < 4; j++) {
                    float v = acc[i][j][r0] + bcol[j];
                    if (RELU) v = fmaxf(v, 0.f);
                    C[(size_t)row * H + bn + wn + j * 16 + lr] = f2bf(v);
                }
            }
        }
    }
}

// ---------------- split-precision MFMA GEMM (MLP tail) ----------------
// AMEAN=true: A comes from poolacc f32; staging applies mean (/count from goff) and
// hi/lo bf16 split in registers — bit-identical to the old pool_finalize2 + load path.
template<int K, int NW, bool RELU, bool F32OUT, bool AMEAN>
__global__ __launch_bounds__(256) void gemm_split(
        const u16* __restrict__ Ahi, const u16* __restrict__ Alo,
        const float* __restrict__ Af, const int* __restrict__ goff,
        const u16* __restrict__ Bhi, const u16* __restrict__ Blo,
        const float* __restrict__ bias,
        u16* __restrict__ Chi, u16* __restrict__ Clo, float* __restrict__ Cf,
        int M) {
    __shared__ __align__(16) u16 sA[2 * 128 * 40];
    __shared__ __align__(16) u16 sB[2 * 128 * 40];
    const int tid = threadIdx.x;
    const int w = tid >> 6, l = tid & 63;
    const int wm = (w & 1) * 64, wn = (w >> 1) * 64;
    const int bm = blockIdx.x * 128, bn = blockIdx.y * 128;
    const int srow = tid >> 2;
    const int schunk = (tid & 3) * 8;
    const int lr = l & 15, lg = (l >> 4) * 8;

    f32x4 acc[4][4] = {};

    for (int k0 = 0; k0 < K; k0 += 32) {
        if constexpr (AMEAN) {
            int r0 = bm + srow, r1 = bm + srow + 64;
            float cf0 = fmaxf((float)(goff[r0 + 1] - goff[r0]), 1.f);
            float cf1 = fmaxf((float)(goff[r1 + 1] - goff[r1]), 1.f);
            u16x8 v0, v1, w0, w1;
#pragma unroll
            for (int j = 0; j < 8; j++) {
                float fv0 = Af[(size_t)r0 * K + k0 + schunk + j] / cf0;
                u16 h0 = f2bf(fv0);
                v0[j] = h0; w0[j] = f2bf(fv0 - bf2f(h0));
                float fv1 = Af[(size_t)r1 * K + k0 + schunk + j] / cf1;
                u16 h1 = f2bf(fv1);
                v1[j] = h1; w1[j] = f2bf(fv1 - bf2f(h1));
            }
            *(u16x8*)&sA[srow * 40 + schunk] = v0;
            *(u16x8*)&sA[(srow + 64) * 40 + schunk] = v1;
            *(u16x8*)&sA[128 * 40 + srow * 40 + schunk] = w0;
            *(u16x8*)&sA[128 * 40 + (srow + 64) * 40 + schunk] = w1;
        } else {
            int r0 = bm + srow, r1 = bm + srow + 64;
            u16x8 v0 = {}, v1 = {}, w0 = {}, w1 = {};
            if (r0 < M) {
                v0 = *(const u16x8*)&Ahi[(size_t)r0 * K + k0 + schunk];
                w0 = *(const u16x8*)&Alo[(size_t)r0 * K + k0 + schunk];
            }
            if (r1 < M) {
                v1 = *(const u16x8*)&Ahi[(size_t)r1 * K + k0 + schunk];
                w1 = *(const u16x8*)&Alo[(size_t)r1 * K + k0 + schunk];
            }
            *(u16x8*)&sA[srow * 40 + schunk] = v0;
            *(u16x8*)&sA[(srow + 64) * 40 + schunk] = v1;
            *(u16x8*)&sA[128 * 40 + srow * 40 + schunk] = w0;
            *(u16x8*)&sA[128 * 40 + (srow + 64) * 40 + schunk] = w1;
        }
        {
            int n0 = bn + srow, n1 = bn + srow + 64;
            *(u16x8*)&sB[srow * 40 + schunk] = *(const u16x8*)&Bhi[(size_t)n0 * K + k0 + schunk];
            *(u16x8*)&sB[(srow + 64) * 40 + schunk] = *(const u16x8*)&Bhi[(size_t)n1 * K + k0 + schunk];
            *(u16x8*)&sB[128 * 40 + srow * 40 + schunk] = *(const u16x8*)&Blo[(size_t)n0 * K + k0 + schunk];
            *(u16x8*)&sB[128 * 40 + (srow + 64) * 40 + schunk] = *(const u16x8*)&Blo[(size_t)n1 * K + k0 + schunk];
        }
        __syncthreads();

        s16x8 af[4], al[4], bh[4], bl[4];
#pragma unroll
        for (int i = 0; i < 4; i++) {
            af[i] = __builtin_bit_cast(s16x8, *(const u16x8*)&sA[(wm + i * 16 + lr) * 40 + lg]);
            al[i] = __builtin_bit_cast(s16x8, *(const u16x8*)&sA[128 * 40 + (wm + i * 16 + lr) * 40 + lg]);
        }
#pragma unroll
        for (int j = 0; j < 4; j++) {
            bh[j] = __builtin_bit_cast(s16x8, *(const u16x8*)&sB[(wn + j * 16 + lr) * 40 + lg]);
            bl[j] = __builtin_bit_cast(s16x8, *(const u16x8*)&sB[128 * 40 + (wn + j * 16 + lr) * 40 + lg]);
        }
#pragma unroll
        for (int i = 0; i < 4; i++) {
#pragma unroll
            for (int j = 0; j < 4; j++) {
                acc[i][j] = __builtin_amdgcn_mfma_f32_16x16x32_bf16(af[i], bh[j], acc[i][j], 0, 0, 0);
                acc[i][j] = __builtin_amdgcn_mfma_f32_16x16x32_bf16(af[i], bl[j], acc[i][j], 0, 0, 0);
                acc[i][j] = __builtin_amdgcn_mfma_f32_16x16x32_bf16(al[i], bh[j], acc[i][j], 0, 0, 0);
            }
        }
        __syncthreads();
    }

    float bcol[4];
#pragma unroll
    for (int j = 0; j < 4; j++) bcol[j] = bias[bn + wn + j * 16 + lr];

    const int lq = (l >> 4) * 4;
#pragma unroll
    for (int i = 0; i < 4; i++) {
#pragma unroll
        for (int r0 = 0; r0 < 4; r0++) {
            int row = bm + wm + i * 16 + lq + r0;
            if (row < M) {
#pragma unroll
                for (int j = 0; j < 4; j++) {
                    float v = acc[i][j][r0] + bcol[j];
                    if (RELU) v = fmaxf(v, 0.f);
                    size_t idx = (size_t)row * NW + bn + wn + j * 16 + lr;
                    if (F32OUT) {
                        Cf[idx] = v;
                    } else {
                        u16 hv = f2bf(v);
                        Chi[idx] = hv;
                        Clo[idx] = f2bf(v - bf2f(hv));
                    }
                }
            }
        }
    }
}

// ---------------- launch ----------------
extern "C" void kernel_launch(void* const* d_in, const int* in_sizes, int n_in,
                              void* d_out, int out_size, void* d_ws, size_t ws_size,
                              hipStream_t stream) {
    const float* x   = (const float*)d_in[0];
    const int*   src = (const int*)d_in[1];
    const int*   dst = (const int*)d_in[2];
    const int*   bat = (const int*)d_in[3];
    const float* W1  = (const float*)d_in[4];  const float* b1  = (const float*)d_in[5];
    const float* W2  = (const float*)d_in[6];  const float* b2  = (const float*)d_in[7];
    const float* W3  = (const float*)d_in[8];  const float* b3  = (const float*)d_in[9];
    const float* Wm1 = (const float*)d_in[10]; const float* bm1 = (const float*)d_in[11];
    const float* Wm2 = (const float*)d_in[12]; const float* bm2 = (const float*)d_in[13];
    float* out = (float*)d_out;

    char* p = (char*)d_ws;
    auto carve = [&](size_t bytes) -> void* {
        void* r = (void*)p;
        p += (bytes + 511) & ~(size_t)511;
        return r;
    };
    u16*   x_bf    = (u16*)  carve((size_t)N_NODES * F_IN * 2);
    u16*   aggX    = (u16*)  carve((size_t)N_NODES * F_IN * 2);
    u16*   bufA    = (u16*)  carve((size_t)N_NODES * H * 2);
    u16*   bufB    = (u16*)  carve((size_t)N_NODES * H * 2);
    float* dinv    = (float*)carve((size_t)N_NODES * 4);
    int*   degc    = (int*)  carve((size_t)N_NODES * 4);
    int*   rowp    = (int*)  carve((size_t)(N_NODES + 1) * 4);
    int*   cur     = (int*)  carve((size_t)N_NODES * 4);
    u32*   ep4     = (u32*)  carve((size_t)N_EDGES * 4);
    u32*   pack    = (u32*)  carve((size_t)N_NODES * 4);
    int*   partial = (int*)  carve(4096);
    int*   goff    = (int*)  carve((size_t)(G_GR + 1) * 4);
    u16*   Wt1_hi  = (u16*)  carve((size_t)F_IN * H * 2);
    u16*   Wt1_lo  = (u16*)  carve((size_t)F_IN * H * 2);
    u16*   Wt2_hi  = (u16*)  carve((size_t)H * H * 2);
    u16*   Wt2_lo  = (u16*)  carve((size_t)H * H * 2);
    u16*   Wt3_hi  = (u16*)  carve((size_t)H * H * 2);
    u16*   Wt3_lo  = (u16*)  carve((size_t)H * H * 2);
    u16*   Wm1t_hi = (u16*)  carve((size_t)H * NHID * 2);
    u16*   Wm1t_lo = (u16*)  carve((size_t)H * NHID * 2);
    u16*   Wm2t_hi = (u16*)  carve((size_t)NHID * NOUT * 2);
    u16*   Wm2t_lo = (u16*)  carve((size_t)NHID * NOUT * 2);
    u16*   y_hi    = (u16*)  carve((size_t)G_GR * H * 2);
    u16*   y_lo    = (u16*)  carve((size_t)G_GR * H * 2);
    u16*   hd_hi   = (u16*)  carve((size_t)G_GR * NHID * 2);
    u16*   hd_lo   = (u16*)  carve((size_t)G_GR * NHID * 2);
    float* poolacc = (float*)carve((size_t)G_GR * H * 4);

    const int NB = (N_NODES + 255) / 256;

    hipMemsetAsync(degc, 0, (size_t)N_NODES * 4, stream);
    prep_head<<<HEAD_BLKS, 256, 0, stream>>>(dst, degc,
                                             W1, Wt1_hi, Wt1_lo,
                                             W2, Wt2_hi, Wt2_lo,
                                             W3, Wt3_hi, Wt3_lo,
                                             Wm1, Wm1t_hi, Wm1t_lo,
                                             Wm2, Wm2t_hi, Wm2t_lo, bat, goff);
    scan_partial<<<NB, 256, 0, stream>>>(degc, partial);
    scan_offsets<<<1, 512, 0, stream>>>(partial, NB, rowp);
    scan_final_dinv<<<NB, 256, 0, stream>>>(degc, partial, rowp, cur, dinv, pack, poolacc);
    // scatter (packed 4B entries) + split_x freight
    scatter_splitx<<<CD_BLKS + SPX_BLKS, 256, 0, stream>>>(src, dst, pack, cur, ep4, x, x_bf);

    dim3 ggrid((N_NODES + 127) / 128, 2);

    // layer 1: aggregate-first (256B rows), then transform+bias+relu
    gcn_agg128<<<N_NODES / 16, 256, 0, stream>>>(x_bf, rowp, ep4, dinv, aggX);
    gemm_bias<F_IN, true><<<ggrid, 256, 0, stream>>>(aggX, Wt1_hi, Wt1_lo, b1, bufA, N_NODES);
    // layer 2
    gcn_agg256<<<N_NODES / 8, 256, 0, stream>>>(bufA, rowp, ep4, dinv, bufB);
    gemm_bias<H, true><<<ggrid, 256, 0, stream>>>(bufB, Wt2_hi, Wt2_lo, b2, bufA, N_NODES);
    // layer 3 + pool fused (gather form): per-node f32 row -> LDS -> per-graph atomic flush
    gcn_agg_pool<<<N_NODES / 8, 256, 0, stream>>>(bufA, rowp, ep4, dinv, bat, poolacc);

    // tail: y=(poolacc/cnt)W3+b3 (mean+split fused into staging) -> hidden -> out
    dim3 g3(2, 2), gm1(2, 4), gm2(2, 2);
    gemm_split<H, H, false, false, true><<<g3, 256, 0, stream>>>(
        nullptr, nullptr, poolacc, goff, Wt3_hi, Wt3_lo, b3, y_hi, y_lo, nullptr, G_GR);
    gemm_split<H, NHID, true, false, false><<<gm1, 256, 0, stream>>>(
        y_hi, y_lo, nullptr, nullptr, Wm1t_hi, Wm1t_lo, bm1, hd_hi, hd_lo, nullptr, G_GR);
    gemm_split<NHID, NOUT, false, true, false><<<gm2, 256, 0, stream>>>(
        hd_hi, hd_lo, nullptr, nullptr, Wm2t_hi, Wm2t_lo, bm2, nullptr, nullptr, out, G_GR);
}

// Round 6
// 666.997 us; speedup vs baseline: 1.0619x; 1.0441x over previous
//
#include <hip/hip_runtime.h>
#include <hip/hip_bf16.h>

#define N_NODES 100000
#define N_EDGES 1600000
#define F_IN    128
#define H       256
#define NHID    512
#define NOUT    256
#define G_GR    256

typedef unsigned short u16;
typedef unsigned int u32;
typedef __attribute__((ext_vector_type(8))) short s16x8;
typedef __attribute__((ext_vector_type(8))) unsigned short u16x8;
typedef __attribute__((ext_vector_type(4))) float f32x4;

// edge entry encoding: (src:17b | indeg_src:15b). wt recomputed as
// dinv[dst]*rsqrtf(1+deg) — bit-identical to storing the product.
#define SRC_MASK 0x1FFFFu
#define DEG_SHIFT 17

__device__ __forceinline__ float bf2f(u16 u) {
    union { unsigned int i; float f; } v; v.i = ((unsigned int)u) << 16; return v.f;
}
__device__ __forceinline__ u16 f2bf(float f) {
    union { float f; unsigned int i; } v; v.f = f;
    unsigned int x = v.i;
    x += 0x7fffu + ((x >> 16) & 1u);
    return (u16)(x >> 16);
}

// ---------------- head: count_deg (atomics; also records within-bucket pos) + transposes ----
#define CD_BLKS   1563                        // 4 strided edges/thread (R8 known-good form)
#define SPX_BLKS  ((N_NODES * F_IN) / 1024)   // 12500 — carried by scatter kernel
#define T1_TILES  ((F_IN / 64) * (H / 64))    // 8
#define T2_TILES  ((H / 64) * (H / 64))       // 16
#define T3_TILES  ((H / 64) * (H / 64))       // 16
#define TM1_TILES ((H / 64) * (NHID / 64))    // 32
#define TM2_TILES ((NHID / 64) * (NOUT / 64)) // 32
#define HEAD_BLKS (CD_BLKS + T1_TILES + T2_TILES + T3_TILES + TM1_TILES + TM2_TILES + 2)

// 64x64 tile transpose via padded LDS: coalesced f32 reads, coalesced 2B hi/lo stores.
__device__ __forceinline__ void transpose_tile(float (*tile)[65],
        const float* __restrict__ W, u16* __restrict__ thi, u16* __restrict__ tlo,
        int K, int N, int tileIdx) {
    const int ntn = N >> 6;
    const int tk = tileIdx / ntn, tn = tileIdx - tk * ntn;
    const int t = threadIdx.x;
    const int c = t & 63, r4 = t >> 6;
#pragma unroll
    for (int i = 0; i < 64; i += 4)
        tile[r4 + i][c] = W[(size_t)(tk * 64 + r4 + i) * N + tn * 64 + c];
    __syncthreads();
#pragma unroll
    for (int i = 0; i < 64; i += 4) {
        int n = tn * 64 + r4 + i, k = tk * 64 + c;
        float f = tile[c][r4 + i];
        u16 h = f2bf(f);
        thi[(size_t)n * K + k] = h;
        tlo[(size_t)n * K + k] = f2bf(f - bf2f(h));
    }
}

__global__ __launch_bounds__(256) void prep_head(
        const int* __restrict__ dst, int* __restrict__ degc, int* __restrict__ posb,
        const float* __restrict__ W1, u16* __restrict__ t1h, u16* __restrict__ t1l,
        const float* __restrict__ W2, u16* __restrict__ t2h, u16* __restrict__ t2l,
        const float* __restrict__ W3, u16* __restrict__ t3h, u16* __restrict__ t3l,
        const float* __restrict__ Wm1, u16* __restrict__ tm1h, u16* __restrict__ tm1l,
        const float* __restrict__ Wm2, u16* __restrict__ tm2h, u16* __restrict__ tm2l,
        const int* __restrict__ batch, int* __restrict__ goff) {
    __shared__ float tile[64][65];
    int bid = blockIdx.x;
    if (bid < CD_BLKS) {
        int base = bid * 1024 + threadIdx.x;
#pragma unroll
        for (int q = 0; q < 4; q++) {
            int e = base + q * 256;
            if (e < N_EDGES) {
                int pos = atomicAdd(&degc[dst[e]], 1);
                posb[e] = pos;          // within-bucket slot: scatter pass needs no atomics
            }
        }
        return;
    }
    bid -= CD_BLKS;
    if (bid < T1_TILES) { transpose_tile(tile, W1, t1h, t1l, F_IN, H, bid); return; }
    bid -= T1_TILES;
    if (bid < T2_TILES) { transpose_tile(tile, W2, t2h, t2l, H, H, bid); return; }
    bid -= T2_TILES;
    if (bid < T3_TILES) { transpose_tile(tile, W3, t3h, t3l, H, H, bid); return; }
    bid -= T3_TILES;
    if (bid < TM1_TILES) { transpose_tile(tile, Wm1, tm1h, tm1l, H, NHID, bid); return; }
    bid -= TM1_TILES;
    if (bid < TM2_TILES) { transpose_tile(tile, Wm2, tm2h, tm2l, NHID, NOUT, bid); return; }
    bid -= TM2_TILES;
    {
        int g = bid * 256 + threadIdx.x;
        if (g > G_GR) return;
        int lo = 0, hi = N_NODES;
        while (lo < hi) {
            int mid = (lo + hi) >> 1;
            if (batch[mid] < g) lo = mid + 1; else hi = mid;
        }
        goff[g] = lo;
    }
}

// ---------------- scan (CSR rowp) ----------------
__global__ void scan_partial(const int* __restrict__ cnt, int* __restrict__ partial) {
    __shared__ int s[256];
    int t = threadIdx.x;
    int i = blockIdx.x * 256 + t;
    int v = (i < N_NODES) ? cnt[i] : 0;
    s[t] = v; __syncthreads();
    for (int off = 128; off > 0; off >>= 1) {
        if (t < off) s[t] += s[t + off];
        __syncthreads();
    }
    if (t == 0) partial[blockIdx.x] = s[0];
}

__global__ void scan_offsets(int* __restrict__ partial, int nb, int* __restrict__ rowp) {
    __shared__ int s[512];
    int t = threadIdx.x;
    int orig = (t < nb) ? partial[t] : 0;
    s[t] = orig; __syncthreads();
    for (int off = 1; off < 512; off <<= 1) {
        int u = (t >= off) ? s[t - off] : 0;
        __syncthreads();
        s[t] += u;
        __syncthreads();
    }
    if (t < nb) partial[t] = s[t] - orig;
    if (t == 0) rowp[N_NODES] = N_EDGES;
}

// also zeros poolacc (first 256 blocks) — replaces a hipMemsetAsync dispatch
__global__ void scan_final_dinv(const int* __restrict__ cnt, const int* __restrict__ partial,
                                int* __restrict__ rowp, float* __restrict__ dinv,
                                float* __restrict__ poolacc) {
    __shared__ int s[256];
    int t = threadIdx.x;
    int i = blockIdx.x * 256 + t;
    if (i < G_GR * H) poolacc[i] = 0.f;
    int v = (i < N_NODES) ? cnt[i] : 0;
    s[t] = v; __syncthreads();
    for (int off = 1; off < 256; off <<= 1) {
        int u = (t >= off) ? s[t - off] : 0;
        __syncthreads();
        s[t] += u;
        __syncthreads();
    }
    if (i < N_NODES) {
        int r = partial[blockIdx.x] + s[t] - v;
        rowp[i] = r;
        dinv[i] = rsqrtf(1.0f + (float)v);
    }
}

// ---------------- scatter (atomic-free: rowp[d]+posb[e]) + split_x streaming freight --------
__global__ __launch_bounds__(256) void scatter_splitx(
        const int* __restrict__ src, const int* __restrict__ dst,
        const int* __restrict__ degc, const int* __restrict__ rowp,
        const int* __restrict__ posb, u32* __restrict__ ep4,
        const float* __restrict__ x, u16* __restrict__ x_bf) {
    int bid = blockIdx.x;
    if (bid < CD_BLKS) {
        int base = bid * 1024 + threadIdx.x;
#pragma unroll
        for (int q = 0; q < 4; q++) {
            int e = base + q * 256;
            if (e < N_EDGES) {
                int d = dst[e];
                int s = src[e];
                u32 w = (u32)s | ((u32)degc[s] << DEG_SHIFT);
                ep4[rowp[d] + posb[e]] = w;
            }
        }
        return;
    }
    bid -= CD_BLKS;
    {   // split_x: 4 floats/thread, 12500 blocks
        int idx = bid * 256 + threadIdx.x;
        float4 f = *(const float4*)&x[(size_t)idx * 4];
        ushort4 o;
        o.x = f2bf(f.x); o.y = f2bf(f.y); o.z = f2bf(f.z); o.w = f2bf(f.w);
        *(ushort4*)&x_bf[(size_t)idx * 4] = o;
    }
}

// ---------------- aggregation: half-wave (32 lanes x ushort8) per node, H=256 ----------------
__global__ __launch_bounds__(256) void gcn_agg256(
        const u16* __restrict__ in, const int* __restrict__ rowp,
        const u32* __restrict__ ep4, const float* __restrict__ dinv,
        u16* __restrict__ outp) {
    int node = blockIdx.x * 8 + (threadIdx.x >> 5);
    int l = threadIdx.x & 31;
    int beg = rowp[node], end = rowp[node + 1];
    float dnode = dinv[node];
    float a[8] = {};
    int e = beg;
    u32 pr[8];
    bool have = (e + 8 <= end);
    if (have) {
#pragma unroll
        for (int q = 0; q < 8; q++) pr[q] = ep4[e + q];
    }
    while (have) {
        u32 g8[8];
#pragma unroll
        for (int q = 0; q < 8; q++) g8[q] = pr[q];
        int en = e + 8;
        bool haven = (en + 8 <= end);
        if (haven) {
#pragma unroll
            for (int q = 0; q < 8; q++) pr[q] = ep4[en + q];
        }
#pragma unroll
        for (int q = 0; q < 8; q++) {
            u16x8 u = *(const u16x8*)&in[(size_t)(g8[q] & SRC_MASK) * H + l * 8];
            float wt = dnode * rsqrtf(1.0f + (float)(g8[q] >> DEG_SHIFT));
#pragma unroll
            for (int r = 0; r < 8; r++) a[r] += bf2f(u[r]) * wt;
        }
        e = en; have = haven;
    }
    for (; e < end; e++) {
        u32 pe = ep4[e];
        float wt = dnode * rsqrtf(1.0f + (float)(pe >> DEG_SHIFT));
        u16x8 u = *(const u16x8*)&in[(size_t)(pe & SRC_MASK) * H + l * 8];
#pragma unroll
        for (int r = 0; r < 8; r++) a[r] += bf2f(u[r]) * wt;
    }
    u16x8 us = *(const u16x8*)&in[(size_t)node * H + l * 8];
    float dd = dnode * dnode;
    u16x8 o;
#pragma unroll
    for (int r = 0; r < 8; r++) o[r] = f2bf(a[r] + bf2f(us[r]) * dd);
    *(u16x8*)&outp[(size_t)node * H + l * 8] = o;
}

// ---------------- aggregation: quarter-wave (16 lanes x ushort8) per node, F=128 ----------------
__global__ __launch_bounds__(256) void gcn_agg128(
        const u16* __restrict__ in, const int* __restrict__ rowp,
        const u32* __restrict__ ep4, const float* __restrict__ dinv,
        u16* __restrict__ outp) {
    int node = blockIdx.x * 16 + (threadIdx.x >> 4);
    int l = threadIdx.x & 15;
    int beg = rowp[node], end = rowp[node + 1];
    float dnode = dinv[node];
    float a[8] = {};
    int e = beg;
    u32 pr[8];
    bool have = (e + 8 <= end);
    if (have) {
#pragma unroll
        for (int q = 0; q < 8; q++) pr[q] = ep4[e + q];
    }
    while (have) {
        u32 g8[8];
#pragma unroll
        for (int q = 0; q < 8; q++) g8[q] = pr[q];
        int en = e + 8;
        bool haven = (en + 8 <= end);
        if (haven) {
#pragma unroll
            for (int q = 0; q < 8; q++) pr[q] = ep4[en + q];
        }
#pragma unroll
        for (int q = 0; q < 8; q++) {
            u16x8 u = *(const u16x8*)&in[(size_t)(g8[q] & SRC_MASK) * F_IN + l * 8];
            float wt = dnode * rsqrtf(1.0f + (float)(g8[q] >> DEG_SHIFT));
#pragma unroll
            for (int r = 0; r < 8; r++) a[r] += bf2f(u[r]) * wt;
        }
        e = en; have = haven;
    }
    for (; e < end; e++) {
        u32 pe = ep4[e];
        float wt = dnode * rsqrtf(1.0f + (float)(pe >> DEG_SHIFT));
        u16x8 u = *(const u16x8*)&in[(size_t)(pe & SRC_MASK) * F_IN + l * 8];
#pragma unroll
        for (int r = 0; r < 8; r++) a[r] += bf2f(u[r]) * wt;
    }
    u16x8 us = *(const u16x8*)&in[(size_t)node * F_IN + l * 8];
    float dd = dnode * dnode;
    u16x8 o;
#pragma unroll
    for (int r = 0; r < 8; r++) o[r] = f2bf(a[r] + bf2f(us[r]) * dd);
    *(u16x8*)&outp[(size_t)node * F_IN + l * 8] = o;
}

// ---------------- layer-3 fused agg+pool: gather form, no per-node output ----------------
__global__ __launch_bounds__(256) void gcn_agg_pool(
        const u16* __restrict__ in, const int* __restrict__ rowp,
        const u32* __restrict__ ep4, const float* __restrict__ dinv,
        const int* __restrict__ batch, float* __restrict__ poolacc) {
    __shared__ __align__(16) float pacc[8][H];
    __shared__ int gslot[8];
    const int tid = threadIdx.x;
    const int hw = tid >> 5;
    const int l = tid & 31;
    const int node = blockIdx.x * 8 + hw;
    const int gbase = batch[blockIdx.x * 8];

    int beg = rowp[node], end = rowp[node + 1];
    float dnode = dinv[node];
    float a[8] = {};
    int e = beg;
    u32 pr[8];
    bool have = (e + 8 <= end);
    if (have) {
#pragma unroll
        for (int q = 0; q < 8; q++) pr[q] = ep4[e + q];
    }
    while (have) {
        u32 g8[8];
#pragma unroll
        for (int q = 0; q < 8; q++) g8[q] = pr[q];
        int en = e + 8;
        bool haven = (en + 8 <= end);
        if (haven) {
#pragma unroll
            for (int q = 0; q < 8; q++) pr[q] = ep4[en + q];
        }
#pragma unroll
        for (int q = 0; q < 8; q++) {
            u16x8 u = *(const u16x8*)&in[(size_t)(g8[q] & SRC_MASK) * H + l * 8];
            float wt = dnode * rsqrtf(1.0f + (float)(g8[q] >> DEG_SHIFT));
#pragma unroll
            for (int r = 0; r < 8; r++) a[r] += bf2f(u[r]) * wt;
        }
        e = en; have = haven;
    }
    for (; e < end; e++) {
        u32 pe = ep4[e];
        float wt = dnode * rsqrtf(1.0f + (float)(pe >> DEG_SHIFT));
        u16x8 u = *(const u16x8*)&in[(size_t)(pe & SRC_MASK) * H + l * 8];
#pragma unroll
        for (int r = 0; r < 8; r++) a[r] += bf2f(u[r]) * wt;
    }
    u16x8 us = *(const u16x8*)&in[(size_t)node * H + l * 8];
    float dd = dnode * dnode;
    f32x4 lo4, hi4;
#pragma unroll
    for (int r = 0; r < 4; r++) lo4[r] = a[r] + bf2f(us[r]) * dd;
#pragma unroll
    for (int r = 0; r < 4; r++) hi4[r] = a[r + 4] + bf2f(us[r + 4]) * dd;
    *(f32x4*)&pacc[hw][l * 8] = lo4;
    *(f32x4*)&pacc[hw][l * 8 + 4] = hi4;
    if (l == 0) gslot[hw] = batch[node] - gbase;
    __syncthreads();

    // reduce 8 node-rows by graph slot, flush with global f32 atomics
    int smax = gslot[7];          // batch sorted -> slots non-decreasing
    float v[8];
#pragma unroll
    for (int q = 0; q < 8; q++) v[q] = pacc[q][tid];
    for (int s = 0; s <= smax; s++) {
        float acc = 0.f;
#pragma unroll
        for (int q = 0; q < 8; q++)
            if (gslot[q] == s) acc += v[q];
        atomicAdd(&poolacc[(size_t)(gbase + s) * H + tid], acc);
    }
}

// ---------------- MFMA GEMM with bias(+relu) epilogue (node layers) ----------------
template<int K, bool RELU>
__global__ __launch_bounds__(256) void gemm_bias(
        const u16* __restrict__ A,
        const u16* __restrict__ Bhi, const u16* __restrict__ Blo,
        const float* __restrict__ bias, u16* __restrict__ C, int M) {
    __shared__ __align__(16) u16 sA[128 * 40];
    __shared__ __align__(16) u16 sB[2 * 128 * 40];
    const int tid = threadIdx.x;
    const int w = tid >> 6, l = tid & 63;
    const int wm = (w & 1) * 64, wn = (w >> 1) * 64;
    const int bm = blockIdx.x * 128, bn = blockIdx.y * 128;
    const int srow = tid >> 2;
    const int schunk = (tid & 3) * 8;
    const int lr = l & 15, lg = (l >> 4) * 8;

    f32x4 acc[4][4] = {};

    for (int k0 = 0; k0 < K; k0 += 32) {
        {
            int r0 = bm + srow, r1 = bm + srow + 64;
            u16x8 v0 = {}, v1 = {};
            if (r0 < M) v0 = *(const u16x8*)&A[(size_t)r0 * K + k0 + schunk];
            if (r1 < M) v1 = *(const u16x8*)&A[(size_t)r1 * K + k0 + schunk];
            *(u16x8*)&sA[srow * 40 + schunk] = v0;
            *(u16x8*)&sA[(srow + 64) * 40 + schunk] = v1;
        }
        {
            int n0 = bn + srow, n1 = bn + srow + 64;
            *(u16x8*)&sB[srow * 40 + schunk] = *(const u16x8*)&Bhi[(size_t)n0 * K + k0 + schunk];
            *(u16x8*)&sB[(srow + 64) * 40 + schunk] = *(const u16x8*)&Bhi[(size_t)n1 * K + k0 + schunk];
            *(u16x8*)&sB[128 * 40 + srow * 40 + schunk] = *(const u16x8*)&Blo[(size_t)n0 * K + k0 + schunk];
            *(u16x8*)&sB[128 * 40 + (srow + 64) * 40 + schunk] = *(const u16x8*)&Blo[(size_t)n1 * K + k0 + schunk];
        }
        __syncthreads();

        s16x8 af[4], bh[4], bl[4];
#pragma unroll
        for (int i = 0; i < 4; i++)
            af[i] = __builtin_bit_cast(s16x8, *(const u16x8*)&sA[(wm + i * 16 + lr) * 40 + lg]);
#pragma unroll
        for (int j = 0; j < 4; j++) {
            bh[j] = __builtin_bit_cast(s16x8, *(const u16x8*)&sB[(wn + j * 16 + lr) * 40 + lg]);
            bl[j] = __builtin_bit_cast(s16x8, *(const u16x8*)&sB[128 * 40 + (wn + j * 16 + lr) * 40 + lg]);
        }
#pragma unroll
        for (int i = 0; i < 4; i++) {
#pragma unroll
            for (int j = 0; j < 4; j++) {
                acc[i][j] = __builtin_amdgcn_mfma_f32_16x16x32_bf16(af[i], bh[j], acc[i][j], 0, 0, 0);
                acc[i][j] = __builtin_amdgcn_mfma_f32_16x16x32_bf16(af[i], bl[j], acc[i][j], 0, 0, 0);
            }
        }
        __syncthreads();
    }

    float bcol[4];
#pragma unroll
    for (int j = 0; j < 4; j++) bcol[j] = bias[bn + wn + j * 16 + lr];

    const int lq = (l >> 4) * 4;
#pragma unroll
    for (int i = 0; i < 4; i++) {
#pragma unroll
        for (int r0 = 0; r0 < 4; r0++) {
            int row = bm + wm + i * 16 + lq + r0;
            if (row < M) {
#pragma unroll
                for (int j = 0; j < 4; j++) {
                    float v = acc[i][j][r0] + bcol[j];
                    if (RELU) v = fmaxf(v, 0.f);
                    C[(size_t)row * H + bn + wn + j * 16 + lr] = f2bf(v);
                }
            }
        }
    }
}

// ---------------- split-precision MFMA GEMM (MLP tail) ----------------
// AMEAN=true: A comes from poolacc f32; staging applies mean (/count from goff) and
// hi/lo bf16 split in registers — bit-identical to the old pool_finalize2 + load path.
template<int K, int NW, bool RELU, bool F32OUT, bool AMEAN>
__global__ __launch_bounds__(256) void gemm_split(
        const u16* __restrict__ Ahi, const u16* __restrict__ Alo,
        const float* __restrict__ Af, const int* __restrict__ goff,
        const u16* __restrict__ Bhi, const u16* __restrict__ Blo,
        const float* __restrict__ bias,
        u16* __restrict__ Chi, u16* __restrict__ Clo, float* __restrict__ Cf,
        int M) {
    __shared__ __align__(16) u16 sA[2 * 128 * 40];
    __shared__ __align__(16) u16 sB[2 * 128 * 40];
    const int tid = threadIdx.x;
    const int w = tid >> 6, l = tid & 63;
    const int wm = (w & 1) * 64, wn = (w >> 1) * 64;
    const int bm = blockIdx.x * 128, bn = blockIdx.y * 128;
    const int srow = tid >> 2;
    const int schunk = (tid & 3) * 8;
    const int lr = l & 15, lg = (l >> 4) * 8;

    f32x4 acc[4][4] = {};

    for (int k0 = 0; k0 < K; k0 += 32) {
        if constexpr (AMEAN) {
            int r0 = bm + srow, r1 = bm + srow + 64;
            float cf0 = fmaxf((float)(goff[r0 + 1] - goff[r0]), 1.f);
            float cf1 = fmaxf((float)(goff[r1 + 1] - goff[r1]), 1.f);
            u16x8 v0, v1, w0, w1;
#pragma unroll
            for (int j = 0; j < 8; j++) {
                float fv0 = Af[(size_t)r0 * K + k0 + schunk + j] / cf0;
                u16 h0 = f2bf(fv0);
                v0[j] = h0; w0[j] = f2bf(fv0 - bf2f(h0));
                float fv1 = Af[(size_t)r1 * K + k0 + schunk + j] / cf1;
                u16 h1 = f2bf(fv1);
                v1[j] = h1; w1[j] = f2bf(fv1 - bf2f(h1));
            }
            *(u16x8*)&sA[srow * 40 + schunk] = v0;
            *(u16x8*)&sA[(srow + 64) * 40 + schunk] = v1;
            *(u16x8*)&sA[128 * 40 + srow * 40 + schunk] = w0;
            *(u16x8*)&sA[128 * 40 + (srow + 64) * 40 + schunk] = w1;
        } else {
            int r0 = bm + srow, r1 = bm + srow + 64;
            u16x8 v0 = {}, v1 = {}, w0 = {}, w1 = {};
            if (r0 < M) {
                v0 = *(const u16x8*)&Ahi[(size_t)r0 * K + k0 + schunk];
                w0 = *(const u16x8*)&Alo[(size_t)r0 * K + k0 + schunk];
            }
            if (r1 < M) {
                v1 = *(const u16x8*)&Ahi[(size_t)r1 * K + k0 + schunk];
                w1 = *(const u16x8*)&Alo[(size_t)r1 * K + k0 + schunk];
            }
            *(u16x8*)&sA[srow * 40 + schunk] = v0;
            *(u16x8*)&sA[(srow + 64) * 40 + schunk] = v1;
            *(u16x8*)&sA[128 * 40 + srow * 40 + schunk] = w0;
            *(u16x8*)&sA[128 * 40 + (srow + 64) * 40 + schunk] = w1;
        }
        {
            int n0 = bn + srow, n1 = bn + srow + 64;
            *(u16x8*)&sB[srow * 40 + schunk] = *(const u16x8*)&Bhi[(size_t)n0 * K + k0 + schunk];
            *(u16x8*)&sB[(srow + 64) * 40 + schunk] = *(const u16x8*)&Bhi[(size_t)n1 * K + k0 + schunk];
            *(u16x8*)&sB[128 * 40 + srow * 40 + schunk] = *(const u16x8*)&Blo[(size_t)n0 * K + k0 + schunk];
            *(u16x8*)&sB[128 * 40 + (srow + 64) * 40 + schunk] = *(const u16x8*)&Blo[(size_t)n1 * K + k0 + schunk];
        }
        __syncthreads();

        s16x8 af[4], al[4], bh[4], bl[4];
#pragma unroll
        for (int i = 0; i < 4; i++) {
            af[i] = __builtin_bit_cast(s16x8, *(const u16x8*)&sA[(wm + i * 16 + lr) * 40 + lg]);
            al[i] = __builtin_bit_cast(s16x8, *(const u16x8*)&sA[128 * 40 + (wm + i * 16 + lr) * 40 + lg]);
        }
#pragma unroll
        for (int j = 0; j < 4; j++) {
            bh[j] = __builtin_bit_cast(s16x8, *(const u16x8*)&sB[(wn + j * 16 + lr) * 40 + lg]);
            bl[j] = __builtin_bit_cast(s16x8, *(const u16x8*)&sB[128 * 40 + (wn + j * 16 + lr) * 40 + lg]);
        }
#pragma unroll
        for (int i = 0; i < 4; i++) {
#pragma unroll
            for (int j = 0; j < 4; j++) {
                acc[i][j] = __builtin_amdgcn_mfma_f32_16x16x32_bf16(af[i], bh[j], acc[i][j], 0, 0, 0);
                acc[i][j] = __builtin_amdgcn_mfma_f32_16x16x32_bf16(af[i], bl[j], acc[i][j], 0, 0, 0);
                acc[i][j] = __builtin_amdgcn_mfma_f32_16x16x32_bf16(al[i], bh[j], acc[i][j], 0, 0, 0);
            }
        }
        __syncthreads();
    }

    float bcol[4];
#pragma unroll
    for (int j = 0; j < 4; j++) bcol[j] = bias[bn + wn + j * 16 + lr];

    const int lq = (l >> 4) * 4;
#pragma unroll
    for (int i = 0; i < 4; i++) {
#pragma unroll
        for (int r0 = 0; r0 < 4; r0++) {
            int row = bm + wm + i * 16 + lq + r0;
            if (row < M) {
#pragma unroll
                for (int j = 0; j < 4; j++) {
                    float v = acc[i][j][r0] + bcol[j];
                    if (RELU) v = fmaxf(v, 0.f);
                    size_t idx = (size_t)row * NW + bn + wn + j * 16 + lr;
                    if (F32OUT) {
                        Cf[idx] = v;
                    } else {
                        u16 hv = f2bf(v);
                        Chi[idx] = hv;
                        Clo[idx] = f2bf(v - bf2f(hv));
                    }
                }
            }
        }
    }
}

// ---------------- launch ----------------
extern "C" void kernel_launch(void* const* d_in, const int* in_sizes, int n_in,
                              void* d_out, int out_size, void* d_ws, size_t ws_size,
                              hipStream_t stream) {
    const float* x   = (const float*)d_in[0];
    const int*   src = (const int*)d_in[1];
    const int*   dst = (const int*)d_in[2];
    const int*   bat = (const int*)d_in[3];
    const float* W1  = (const float*)d_in[4];  const float* b1  = (const float*)d_in[5];
    const float* W2  = (const float*)d_in[6];  const float* b2  = (const float*)d_in[7];
    const float* W3  = (const float*)d_in[8];  const float* b3  = (const float*)d_in[9];
    const float* Wm1 = (const float*)d_in[10]; const float* bm1 = (const float*)d_in[11];
    const float* Wm2 = (const float*)d_in[12]; const float* bm2 = (const float*)d_in[13];
    float* out = (float*)d_out;

    char* p = (char*)d_ws;
    auto carve = [&](size_t bytes) -> void* {
        void* r = (void*)p;
        p += (bytes + 511) & ~(size_t)511;
        return r;
    };
    u16*   x_bf    = (u16*)  carve((size_t)N_NODES * F_IN * 2);
    u16*   aggX    = (u16*)  carve((size_t)N_NODES * F_IN * 2);
    u16*   bufA    = (u16*)  carve((size_t)N_NODES * H * 2);
    u16*   bufB    = (u16*)  carve((size_t)N_NODES * H * 2);
    float* dinv    = (float*)carve((size_t)N_NODES * 4);
    int*   degc    = (int*)  carve((size_t)N_NODES * 4);
    int*   rowp    = (int*)  carve((size_t)(N_NODES + 1) * 4);
    int*   posb    = (int*)  carve((size_t)N_EDGES * 4);
    u32*   ep4     = (u32*)  carve((size_t)N_EDGES * 4);
    int*   partial = (int*)  carve(4096);
    int*   goff    = (int*)  carve((size_t)(G_GR + 1) * 4);
    u16*   Wt1_hi  = (u16*)  carve((size_t)F_IN * H * 2);
    u16*   Wt1_lo  = (u16*)  carve((size_t)F_IN * H * 2);
    u16*   Wt2_hi  = (u16*)  carve((size_t)H * H * 2);
    u16*   Wt2_lo  = (u16*)  carve((size_t)H * H * 2);
    u16*   Wt3_hi  = (u16*)  carve((size_t)H * H * 2);
    u16*   Wt3_lo  = (u16*)  carve((size_t)H * H * 2);
    u16*   Wm1t_hi = (u16*)  carve((size_t)H * NHID * 2);
    u16*   Wm1t_lo = (u16*)  carve((size_t)H * NHID * 2);
    u16*   Wm2t_hi = (u16*)  carve((size_t)NHID * NOUT * 2);
    u16*   Wm2t_lo = (u16*)  carve((size_t)NHID * NOUT * 2);
    u16*   y_hi    = (u16*)  carve((size_t)G_GR * H * 2);
    u16*   y_lo    = (u16*)  carve((size_t)G_GR * H * 2);
    u16*   hd_hi   = (u16*)  carve((size_t)G_GR * NHID * 2);
    u16*   hd_lo   = (u16*)  carve((size_t)G_GR * NHID * 2);
    float* poolacc = (float*)carve((size_t)G_GR * H * 4);

    const int NB = (N_NODES + 255) / 256;

    hipMemsetAsync(degc, 0, (size_t)N_NODES * 4, stream);
    prep_head<<<HEAD_BLKS, 256, 0, stream>>>(dst, degc, posb,
                                             W1, Wt1_hi, Wt1_lo,
                                             W2, Wt2_hi, Wt2_lo,
                                             W3, Wt3_hi, Wt3_lo,
                                             Wm1, Wm1t_hi, Wm1t_lo,
                                             Wm2, Wm2t_hi, Wm2t_lo, bat, goff);
    scan_partial<<<NB, 256, 0, stream>>>(degc, partial);
    scan_offsets<<<1, 512, 0, stream>>>(partial, NB, rowp);
    scan_final_dinv<<<NB, 256, 0, stream>>>(degc, partial, rowp, dinv, poolacc);
    // scatter (atomic-free placement via rowp+posb) + split_x freight
    scatter_splitx<<<CD_BLKS + SPX_BLKS, 256, 0, stream>>>(src, dst, degc, rowp, posb,
                                                           ep4, x, x_bf);

    dim3 ggrid((N_NODES + 127) / 128, 2);

    // layer 1: aggregate-first (256B rows), then transform+bias+relu
    gcn_agg128<<<N_NODES / 16, 256, 0, stream>>>(x_bf, rowp, ep4, dinv, aggX);
    gemm_bias<F_IN, true><<<ggrid, 256, 0, stream>>>(aggX, Wt1_hi, Wt1_lo, b1, bufA, N_NODES);
    // layer 2
    gcn_agg256<<<N_NODES / 8, 256, 0, stream>>>(bufA, rowp, ep4, dinv, bufB);
    gemm_bias<H, true><<<ggrid, 256, 0, stream>>>(bufB, Wt2_hi, Wt2_lo, b2, bufA, N_NODES);
    // layer 3 + pool fused (gather form): per-node f32 row -> LDS -> per-graph atomic flush
    gcn_agg_pool<<<N_NODES / 8, 256, 0, stream>>>(bufA, rowp, ep4, dinv, bat, poolacc);

    // tail: y=(poolacc/cnt)W3+b3 (mean+split fused into staging) -> hidden -> out
    dim3 g3(2, 2), gm1(2, 4), gm2(2, 2);
    gemm_split<H, H, false, false, true><<<g3, 256, 0, stream>>>(
        nullptr, nullptr, poolacc, goff, Wt3_hi, Wt3_lo, b3, y_hi, y_lo, nullptr, G_GR);
    gemm_split<H, NHID, true, false, false><<<gm1, 256, 0, stream>>>(
        y_hi, y_lo, nullptr, nullptr, Wm1t_hi, Wm1t_lo, bm1, hd_hi, hd_lo, nullptr, G_GR);
    gemm_split<NHID, NOUT, false, true, false><<<gm2, 256, 0, stream>>>(
        hd_hi, hd_lo, nullptr, nullptr, Wm2t_hi, Wm2t_lo, bm2, nullptr, nullptr, out, G_GR);
}